// Round 14
// baseline (1680.815 us; speedup 1.0000x reference)
//
#include <hip/hip_runtime.h>
#include <cstddef>

#define DIM    128
#define DIM2   256
#define NGRAPH 1024
#define NTASK  10
#define NEV    4
#define BNEPS  1e-5f
#define GAMMA_ 0.4f

typedef __attribute__((ext_vector_type(2))) float f32x2;
typedef __attribute__((ext_vector_type(4))) float f32x4;
typedef __attribute__((ext_vector_type(8))) short s16x8;

static __device__ __forceinline__ float relu_(float v) { return v > 0.f ? v : 0.f; }
static __device__ __forceinline__ unsigned short f2b(float f) {
    unsigned int u = __float_as_uint(f);
    unsigned int r = (u + 0x7fffu + ((u >> 16) & 1u)) >> 16;
    return (unsigned short)r;
}
static __device__ __forceinline__ float b2f(unsigned short b) {
    return __uint_as_float(((unsigned int)b) << 16);
}
static __device__ __forceinline__ unsigned int pk(float a, float b) {
    return (unsigned int)f2b(a) | ((unsigned int)f2b(b) << 16);
}

// ---------------- CSR build ----------------
__global__ void k_count_deg(const int* __restrict__ dst, int* __restrict__ deg, int E) {
    int e = blockIdx.x * blockDim.x + threadIdx.x;
    if (e < E) atomicAdd(&deg[dst[e]], 1);
}

__global__ void k_scan_block(const int* __restrict__ deg, int* __restrict__ incl,
                             int* __restrict__ bsum, int n) {
    __shared__ int s[1024];
    int i = blockIdx.x * 1024 + threadIdx.x;
    int v = (i < n) ? deg[i] : 0;
    s[threadIdx.x] = v;
    __syncthreads();
    for (int off = 1; off < 1024; off <<= 1) {
        int t = (threadIdx.x >= off) ? s[threadIdx.x - off] : 0;
        __syncthreads();
        s[threadIdx.x] += t;
        __syncthreads();
    }
    if (i < n) incl[i] = s[threadIdx.x];
    if (threadIdx.x == 1023) bsum[blockIdx.x] = s[1023];
}

__global__ void k_scan_bsum(const int* __restrict__ bsum, int* __restrict__ boff, int nb) {
    __shared__ int s[128];
    int t = threadIdx.x;
    s[t] = (t < nb) ? bsum[t] : 0;
    __syncthreads();
    for (int off = 1; off < 128; off <<= 1) {
        int v = (t >= off) ? s[t - off] : 0;
        __syncthreads();
        s[t] += v;
        __syncthreads();
    }
    if (t < nb) boff[t] = (t == 0) ? 0 : s[t - 1];
}

__global__ void k_scan_final(const int* __restrict__ incl, const int* __restrict__ deg,
                             const int* __restrict__ boff, int* __restrict__ rowptr,
                             int* __restrict__ cursor, int n) {
    int i = blockIdx.x * blockDim.x + threadIdx.x;
    if (i < n) {
        int v = incl[i] + boff[i >> 10];
        rowptr[i + 1] = v;
        cursor[i] = v - deg[i];
    }
    if (i == 0) rowptr[0] = 0;
}

__global__ void k_fill_csr(const int* __restrict__ src, const int* __restrict__ dst,
                           const int* __restrict__ ea, int* __restrict__ cursor,
                           int* __restrict__ src_s, int* __restrict__ ea_s, int E) {
    int e = blockIdx.x * blockDim.x + threadIdx.x;
    if (e < E) {
        int p = atomicAdd(&cursor[dst[e]], 1);
        src_s[p] = src[e];
        ea_s[p]  = ea[e];
    }
}

__global__ void k_graph_ptr(const int* __restrict__ batch, int* __restrict__ gptr, int n, int B) {
    int g = blockIdx.x * blockDim.x + threadIdx.x;
    if (g > B) return;
    int lo = 0, hi = n;
    while (lo < hi) {
        int mid = (lo + hi) >> 1;
        if (batch[mid] < g) lo = mid + 1; else hi = mid;
    }
    gptr[g] = lo;
}

// ---------------- weight convert: Wt[l][c][k] = bf16(W[l][k][c]) ----------------
__global__ void k_wconv(const float* __restrict__ W, unsigned short* __restrict__ Wt,
                        int L, int K, int COUT) {
    long long i = (long long)blockIdx.x * 256 + threadIdx.x;
    long long total = (long long)L * K * COUT;
    if (i >= total) return;
    int l = (int)(i / (K * COUT));
    int rem = (int)(i % (K * COUT));
    int c = rem / K, k = rem % K;
    Wt[i] = f2b(W[(size_t)l * K * COUT + (size_t)k * COUT + c]);
}

// ---------------- node init (x4 vectorized) ----------------
__global__ void k_h0(const float* __restrict__ x, const float* __restrict__ W,
                     const float* __restrict__ b, float* __restrict__ h,
                     unsigned short* __restrict__ hb, int n) {
    int idx = blockIdx.x * blockDim.x + threadIdx.x;
    if (idx >= n * (DIM / 4)) return;
    int node = idx >> 5;
    int c4 = (idx & 31) << 2;
    const float* xr = x + (size_t)node * 4;
    float x0 = xr[0], x1 = xr[1], x2 = xr[2], x3 = xr[3];
    const float4 w0 = *(const float4*)(W + c4);
    const float4 w1 = *(const float4*)(W + DIM + c4);
    const float4 w2 = *(const float4*)(W + 2 * DIM + c4);
    const float4 w3 = *(const float4*)(W + 3 * DIM + c4);
    const float4 bv = *(const float4*)(b + c4);
    float4 o;
    o.x = bv.x + x0 * w0.x + x1 * w1.x + x2 * w2.x + x3 * w3.x;
    o.y = bv.y + x0 * w0.y + x1 * w1.y + x2 * w2.y + x3 * w3.y;
    o.z = bv.z + x0 * w0.z + x1 * w1.z + x2 * w2.z + x3 * w3.z;
    o.w = bv.w + x0 * w0.w + x1 * w1.w + x2 * w2.w + x3 * w3.w;
    size_t off = (size_t)node * DIM + c4;
    *(float4*)(h + off) = o;
    if (hb) {
        uint2 ob;
        ob.x = pk(o.x, o.y);
        ob.y = pk(o.z, o.w);
        *(uint2*)(hb + off) = ob;
    }
}

// ---------------- edge aggregation, fp32 h -> fp32 z (8-edge unrolled) ----------------
__global__ __launch_bounds__(256) void k_aggregate(
    const float* __restrict__ h, const int* __restrict__ rowptr,
    const int* __restrict__ src_s, const int* __restrict__ ea_s,
    const float* __restrict__ emb, const float* __restrict__ eps_arr, int l,
    float* __restrict__ zout, int n) {
    __shared__ float semb[NEV * DIM];
    int t = threadIdx.x;
    for (int i = t; i < NEV * DIM; i += 256) semb[i] = emb[(size_t)l * NEV * DIM + i];
    __syncthreads();
    int grp = t >> 5, lane = t & 31;
    int node = blockIdx.x * 8 + grp;
    if (node >= n) return;
    float eps1 = 1.0f + eps_arr[l];
    int beg = rowptr[node], end = rowptr[node + 1];
    int c = lane << 2;
    float4 acc = {0.f, 0.f, 0.f, 0.f};
    int e = beg;
    for (; e + 8 <= end; e += 8) {
        int sE[8], aE[8];
#pragma unroll
        for (int j = 0; j < 8; ++j) { sE[j] = src_s[e + j]; aE[j] = ea_s[e + j]; }
        float4 hv[8];
#pragma unroll
        for (int j = 0; j < 8; ++j) hv[j] = *(const float4*)(h + (size_t)sE[j] * DIM + c);
#pragma unroll
        for (int j = 0; j < 8; ++j) {
            const float4 ev = *(const float4*)(semb + aE[j] * DIM + c);
            acc.x += relu_(hv[j].x + ev.x);
            acc.y += relu_(hv[j].y + ev.y);
            acc.z += relu_(hv[j].z + ev.z);
            acc.w += relu_(hv[j].w + ev.w);
        }
    }
    for (; e + 4 <= end; e += 4) {
        int s0 = src_s[e], s1 = src_s[e + 1], s2 = src_s[e + 2], s3 = src_s[e + 3];
        int a0 = ea_s[e], a1 = ea_s[e + 1], a2 = ea_s[e + 2], a3 = ea_s[e + 3];
        const float4 hv0 = *(const float4*)(h + (size_t)s0 * DIM + c);
        const float4 hv1 = *(const float4*)(h + (size_t)s1 * DIM + c);
        const float4 hv2 = *(const float4*)(h + (size_t)s2 * DIM + c);
        const float4 hv3 = *(const float4*)(h + (size_t)s3 * DIM + c);
        const float4 ev0 = *(const float4*)(semb + a0 * DIM + c);
        const float4 ev1 = *(const float4*)(semb + a1 * DIM + c);
        const float4 ev2 = *(const float4*)(semb + a2 * DIM + c);
        const float4 ev3 = *(const float4*)(semb + a3 * DIM + c);
        acc.x += relu_(hv0.x + ev0.x); acc.y += relu_(hv0.y + ev0.y);
        acc.z += relu_(hv0.z + ev0.z); acc.w += relu_(hv0.w + ev0.w);
        acc.x += relu_(hv1.x + ev1.x); acc.y += relu_(hv1.y + ev1.y);
        acc.z += relu_(hv1.z + ev1.z); acc.w += relu_(hv1.w + ev1.w);
        acc.x += relu_(hv2.x + ev2.x); acc.y += relu_(hv2.y + ev2.y);
        acc.z += relu_(hv2.z + ev2.z); acc.w += relu_(hv2.w + ev2.w);
        acc.x += relu_(hv3.x + ev3.x); acc.y += relu_(hv3.y + ev3.y);
        acc.z += relu_(hv3.z + ev3.z); acc.w += relu_(hv3.w + ev3.w);
    }
    for (; e < end; ++e) {
        int s = src_s[e];
        int a = ea_s[e];
        const float4 hv = *(const float4*)(h + (size_t)s * DIM + c);
        const float4 ev = *(const float4*)(semb + a * DIM + c);
        acc.x += relu_(hv.x + ev.x);
        acc.y += relu_(hv.y + ev.y);
        acc.z += relu_(hv.z + ev.z);
        acc.w += relu_(hv.w + ev.w);
    }
    const float4 hn = *(const float4*)(h + (size_t)node * DIM + c);
    float4 o;
    o.x = eps1 * hn.x + acc.x;
    o.y = eps1 * hn.y + acc.y;
    o.z = eps1 * hn.z + acc.z;
    o.w = eps1 * hn.w + acc.w;
    *(float4*)(zout + (size_t)node * DIM + c) = o;
}

// ---------------- edge aggregation, bf16 h -> bf16 z (8-edge unrolled) ----------------
__global__ __launch_bounds__(256) void k_agg_bf(
    const unsigned short* __restrict__ hb, const int* __restrict__ rowptr,
    const int* __restrict__ src_s, const int* __restrict__ ea_s,
    const float* __restrict__ emb, const float* __restrict__ eps_arr, int l,
    unsigned short* __restrict__ zb, int n) {
    __shared__ float semb[NEV * DIM];
    int t = threadIdx.x;
    for (int i = t; i < NEV * DIM; i += 256) semb[i] = emb[(size_t)l * NEV * DIM + i];
    __syncthreads();
    int grp = t >> 5, lane = t & 31;
    int node = blockIdx.x * 8 + grp;
    if (node >= n) return;
    float eps1 = 1.0f + eps_arr[l];
    int beg = rowptr[node], end = rowptr[node + 1];
    int c = lane << 2;
    float ax = 0.f, ay = 0.f, az = 0.f, aw = 0.f;
    int e = beg;
    for (; e + 8 <= end; e += 8) {
        int sE[8], aE[8];
#pragma unroll
        for (int j = 0; j < 8; ++j) { sE[j] = src_s[e + j]; aE[j] = ea_s[e + j]; }
        ushort4 hv[8];
#pragma unroll
        for (int j = 0; j < 8; ++j) hv[j] = *(const ushort4*)(hb + (size_t)sE[j] * DIM + c);
#pragma unroll
        for (int j = 0; j < 8; ++j) {
            const float4 ev = *(const float4*)(semb + aE[j] * DIM + c);
            ax += relu_(b2f(hv[j].x) + ev.x);
            ay += relu_(b2f(hv[j].y) + ev.y);
            az += relu_(b2f(hv[j].z) + ev.z);
            aw += relu_(b2f(hv[j].w) + ev.w);
        }
    }
    for (; e + 4 <= end; e += 4) {
        int s0 = src_s[e], s1 = src_s[e + 1], s2 = src_s[e + 2], s3 = src_s[e + 3];
        int a0 = ea_s[e], a1 = ea_s[e + 1], a2 = ea_s[e + 2], a3 = ea_s[e + 3];
        ushort4 hv0 = *(const ushort4*)(hb + (size_t)s0 * DIM + c);
        ushort4 hv1 = *(const ushort4*)(hb + (size_t)s1 * DIM + c);
        ushort4 hv2 = *(const ushort4*)(hb + (size_t)s2 * DIM + c);
        ushort4 hv3 = *(const ushort4*)(hb + (size_t)s3 * DIM + c);
        const float4 ev0 = *(const float4*)(semb + a0 * DIM + c);
        const float4 ev1 = *(const float4*)(semb + a1 * DIM + c);
        const float4 ev2 = *(const float4*)(semb + a2 * DIM + c);
        const float4 ev3 = *(const float4*)(semb + a3 * DIM + c);
        ax += relu_(b2f(hv0.x) + ev0.x); ay += relu_(b2f(hv0.y) + ev0.y);
        az += relu_(b2f(hv0.z) + ev0.z); aw += relu_(b2f(hv0.w) + ev0.w);
        ax += relu_(b2f(hv1.x) + ev1.x); ay += relu_(b2f(hv1.y) + ev1.y);
        az += relu_(b2f(hv1.z) + ev1.z); aw += relu_(b2f(hv1.w) + ev1.w);
        ax += relu_(b2f(hv2.x) + ev2.x); ay += relu_(b2f(hv2.y) + ev2.y);
        az += relu_(b2f(hv2.z) + ev2.z); aw += relu_(b2f(hv2.w) + ev2.w);
        ax += relu_(b2f(hv3.x) + ev3.x); ay += relu_(b2f(hv3.y) + ev3.y);
        az += relu_(b2f(hv3.z) + ev3.z); aw += relu_(b2f(hv3.w) + ev3.w);
    }
    for (; e < end; ++e) {
        int s = src_s[e];
        int a = ea_s[e];
        ushort4 hv = *(const ushort4*)(hb + (size_t)s * DIM + c);
        const float4 ev = *(const float4*)(semb + a * DIM + c);
        ax += relu_(b2f(hv.x) + ev.x);
        ay += relu_(b2f(hv.y) + ev.y);
        az += relu_(b2f(hv.z) + ev.z);
        aw += relu_(b2f(hv.w) + ev.w);
    }
    ushort4 hn = *(const ushort4*)(hb + (size_t)node * DIM + c);
    uint2 o;
    o.x = pk(eps1 * b2f(hn.x) + ax, eps1 * b2f(hn.y) + ay);
    o.y = pk(eps1 * b2f(hn.z) + az, eps1 * b2f(hn.w) + aw);
    *(uint2*)(zb + (size_t)node * DIM + c) = o;
}

// ---------------- fp32 tiled matmul + fused BN-stats epilogue ----------------
// 64x128 tile, BK=32, thread 4x(4+4); gload staging (W linear, A chunk-XOR swizzled).
template <int K, int COUT, bool TRANS, bool STATS>
__global__ __launch_bounds__(256) void k_mmf(
    const float* __restrict__ A, const float* __restrict__ W,
    const float* __restrict__ bias, const float* __restrict__ scl,
    const float* __restrict__ shf, float* __restrict__ C,
    float* __restrict__ psum, float* __restrict__ psq, int nrows) {
    __shared__ float Asl[64 * 32];    // 8 KB, swizzled
    __shared__ float Wsl[32 * 128];   // 16 KB, linear
    const int t = threadIdx.x;
    const int lane = t & 63, wid = t >> 6;
    const int row0 = blockIdx.x * 64;
    const int col0 = blockIdx.y * 128;
    const int tc = t & 15;
    const int tr = t >> 4;
    f32x4 acc[4][2] = {};
    for (int k0 = 0; k0 < K; k0 += 32) {
        if (!TRANS) {
#pragma unroll
            for (int i = 0; i < 2; ++i) {
                int g = i * 4 + wid;
                int s = g * 64 + lane;
                int r = s >> 3, c = s & 7;
                int gr = row0 + r; if (gr >= nrows) gr = nrows - 1;
                int cs = c ^ ((r & 7) ^ ((r >> 3) & 7));
                const float* src = A + (size_t)gr * K + k0 + (cs << 2);
                __builtin_amdgcn_global_load_lds((const unsigned int*)src,
                    (unsigned int*)((char*)Asl + g * 1024), 16, 0, 0);
            }
        } else {
#pragma unroll
            for (int j = 0; j < 2; ++j) {
                int ff = j * 256 + t;
                int r = ff >> 3;
                int kc = (ff & 7) << 2;
                int grow = row0 + r;
                float4 v = {0.f, 0.f, 0.f, 0.f};
                if (grow < nrows) {
                    v = *(const float4*)(A + (size_t)grow * K + (k0 + kc));
                    const float4 s4 = *(const float4*)(scl + k0 + kc);
                    const float4 h4 = *(const float4*)(shf + k0 + kc);
                    v.x = relu_(v.x * s4.x + h4.x);
                    v.y = relu_(v.y * s4.y + h4.y);
                    v.z = relu_(v.z * s4.z + h4.z);
                    v.w = relu_(v.w * s4.w + h4.w);
                }
                int byte = (r * 128 + kc * 4) ^ ((((r & 7) ^ ((r >> 3) & 7))) << 4);
                *(float4*)((char*)Asl + byte) = v;
            }
        }
#pragma unroll
        for (int i = 0; i < 4; ++i) {
            int g = i * 4 + wid;
            int s = g * 64 + lane;
            int kr = s >> 5, c = s & 31;
            const float* src = W + (size_t)(k0 + kr) * COUT + col0 + (c << 2);
            __builtin_amdgcn_global_load_lds((const unsigned int*)src,
                (unsigned int*)((char*)Wsl + g * 1024), 16, 0, 0);
        }
        __syncthreads();
#pragma unroll
        for (int k4 = 0; k4 < 32; k4 += 4) {
            f32x4 a4[4];
#pragma unroll
            for (int r = 0; r < 4; ++r) {
                int row = (tr << 2) + r;
                int byte = (row * 128 + k4 * 4) ^ ((((row & 7) ^ ((row >> 3) & 7))) << 4);
                a4[r] = *(const f32x4*)((const char*)Asl + byte);
            }
#pragma unroll
            for (int kk = 0; kk < 4; ++kk) {
                const f32x4 w0 = *(const f32x4*)(Wsl + (k4 + kk) * 128 + (tc << 2));
                const f32x4 w1 = *(const f32x4*)(Wsl + (k4 + kk) * 128 + 64 + (tc << 2));
#pragma unroll
                for (int r = 0; r < 4; ++r) {
                    float a = a4[r][kk];
                    f32x4 av = {a, a, a, a};
                    acc[r][0] = __builtin_elementwise_fma(av, w0, acc[r][0]);
                    acc[r][1] = __builtin_elementwise_fma(av, w1, acc[r][1]);
                }
            }
        }
        __syncthreads();
    }
    const f32x4 b0 = *(const f32x4*)(bias + col0 + (tc << 2));
    const f32x4 b1 = *(const f32x4*)(bias + col0 + 64 + (tc << 2));
    float s0[4] = {}, q0[4] = {}, s1[4] = {}, q1[4] = {};
#pragma unroll
    for (int r = 0; r < 4; ++r) {
        int row = row0 + (tr << 2) + r;
        if (row < nrows) {
            f32x4 o0 = acc[r][0] + b0;
            f32x4 o1 = acc[r][1] + b1;
            *(f32x4*)(C + (size_t)row * COUT + col0 + (tc << 2)) = o0;
            *(f32x4*)(C + (size_t)row * COUT + col0 + 64 + (tc << 2)) = o1;
            if (STATS) {
#pragma unroll
                for (int j = 0; j < 4; ++j) {
                    s0[j] += o0[j]; q0[j] += o0[j] * o0[j];
                    s1[j] += o1[j]; q1[j] += o1[j] * o1[j];
                }
            }
        }
    }
    if (STATS) {
        float* ls1 = Wsl;   // 16 x 128
        float* ls2 = Asl;   // 16 x 128
        __syncthreads();
#pragma unroll
        for (int j = 0; j < 4; ++j) {
            ls1[tr * 128 + (tc << 2) + j] = s0[j];
            ls1[tr * 128 + 64 + (tc << 2) + j] = s1[j];
            ls2[tr * 128 + (tc << 2) + j] = q0[j];
            ls2[tr * 128 + 64 + (tc << 2) + j] = q1[j];
        }
        __syncthreads();
        if (t < 128) {
            float ss = 0.f, qq = 0.f;
#pragma unroll
            for (int g = 0; g < 16; ++g) { ss += ls1[g * 128 + t]; qq += ls2[g * 128 + t]; }
            psum[(size_t)blockIdx.x * COUT + col0 + t] = ss;
            psq[(size_t)blockIdx.x * COUT + col0 + t]  = qq;
        }
    }
}

// ---------------- bf16 MFMA matmul (encoder) + fused BN-stats ----------------
// 128x64 tile, BK=64, 4 waves, wave tile 64x32, acc 4x2; gload staging.
template <int K, int COUT, bool TRANS, bool OUT_BF, bool STATS>
__global__ __launch_bounds__(256) void k_mm_bf(
    const unsigned short* __restrict__ A, const unsigned short* __restrict__ Wt,
    const float* __restrict__ bias, const float* __restrict__ scl,
    const float* __restrict__ shf, void* __restrict__ Cout,
    float* __restrict__ psum, float* __restrict__ psq, int nrows) {
    __shared__ unsigned short As[128 * 64];  // row-major, XOR-swizzled
    __shared__ unsigned short Bs[64 * 64];   // Bt[col][k], XOR-swizzled
    const int t = threadIdx.x;
    const int row0 = blockIdx.x * 128;
    const int col0 = blockIdx.y * 64;
    const int wid = t >> 6, lane = t & 63;
    const int wm = wid & 1, wn = wid >> 1;
    const int lr = lane & 15, lk = lane >> 4;
    f32x4 acc[4][2] = {};
    for (int k0 = 0; k0 < K; k0 += 64) {
        // ---- stage A (128 rows x 64 k bf16) ----
        if (!TRANS) {
#pragma unroll
            for (int i = 0; i < 4; ++i) {
                int g = i * 4 + wid;
                int s = g * 64 + lane;
                int r = s >> 3, c = s & 7;
                int gr = row0 + r; if (gr >= nrows) gr = nrows - 1;
                int cs = c ^ (r & 7);
                const unsigned short* src = A + (size_t)gr * K + k0 + (cs << 3);
                __builtin_amdgcn_global_load_lds((const unsigned int*)src,
                    (unsigned int*)((char*)As + g * 1024), 16, 0, 0);
            }
        } else {
#pragma unroll
            for (int i = 0; i < 4; ++i) {
                int idx = i * 256 + t;
                int r = idx >> 3;
                int kc = (idx & 7) * 8;
                int gr = row0 + r;
                uint4 v = {0u, 0u, 0u, 0u};
                if (gr < nrows) {
                    uint4 raw = *(const uint4*)(A + (size_t)gr * K + k0 + kc);
                    const float4 s0 = *(const float4*)(scl + k0 + kc);
                    const float4 s1 = *(const float4*)(scl + k0 + kc + 4);
                    const float4 h0 = *(const float4*)(shf + k0 + kc);
                    const float4 h1 = *(const float4*)(shf + k0 + kc + 4);
                    float v0 = relu_(b2f((unsigned short)(raw.x & 0xffff)) * s0.x + h0.x);
                    float v1 = relu_(b2f((unsigned short)(raw.x >> 16))    * s0.y + h0.y);
                    float v2 = relu_(b2f((unsigned short)(raw.y & 0xffff)) * s0.z + h0.z);
                    float v3 = relu_(b2f((unsigned short)(raw.y >> 16))    * s0.w + h0.w);
                    float v4 = relu_(b2f((unsigned short)(raw.z & 0xffff)) * s1.x + h1.x);
                    float v5 = relu_(b2f((unsigned short)(raw.z >> 16))    * s1.y + h1.y);
                    float v6 = relu_(b2f((unsigned short)(raw.w & 0xffff)) * s1.z + h1.z);
                    float v7 = relu_(b2f((unsigned short)(raw.w >> 16))    * s1.w + h1.w);
                    v.x = pk(v0, v1); v.y = pk(v2, v3); v.z = pk(v4, v5); v.w = pk(v6, v7);
                }
                int byte = (r * 128 + kc * 2) ^ ((r & 7) << 4);
                *(uint4*)((char*)As + byte) = v;
            }
        }
        // ---- stage B (64 cols x 64 k bf16), gload ----
#pragma unroll
        for (int i = 0; i < 2; ++i) {
            int g = i * 4 + wid;
            int s = g * 64 + lane;
            int c = s >> 3, kc = s & 7;
            int ks = kc ^ (c & 7);
            const unsigned short* src = Wt + (size_t)(col0 + c) * K + k0 + (ks << 3);
            __builtin_amdgcn_global_load_lds((const unsigned int*)src,
                (unsigned int*)((char*)Bs + g * 1024), 16, 0, 0);
        }
        __syncthreads();
#pragma unroll
        for (int kk = 0; kk < 64; kk += 32) {
            s16x8 bfrag[2];
#pragma unroll
            for (int n = 0; n < 2; ++n) {
                int c = wn * 32 + n * 16 + lr;
                int byte = (c * 128 + (kk + lk * 8) * 2) ^ ((c & 7) << 4);
                bfrag[n] = *(const s16x8*)((const char*)Bs + byte);
            }
#pragma unroll
            for (int m = 0; m < 4; ++m) {
                int r = wm * 64 + m * 16 + lr;
                int byte = (r * 128 + (kk + lk * 8) * 2) ^ ((r & 7) << 4);
                s16x8 afrag = *(const s16x8*)((const char*)As + byte);
                acc[m][0] = __builtin_amdgcn_mfma_f32_16x16x32_bf16(afrag, bfrag[0], acc[m][0], 0, 0, 0);
                acc[m][1] = __builtin_amdgcn_mfma_f32_16x16x32_bf16(afrag, bfrag[1], acc[m][1], 0, 0, 0);
            }
        }
        __syncthreads();
    }
    float* ls1 = (float*)&Bs[0];      // 64 cols x 8 slots
    float* ls2 = ls1 + 512;
#pragma unroll
    for (int n = 0; n < 2; ++n) {
        int col_local = wn * 32 + n * 16 + lr;
        int col = col0 + col_local;
        float bv = bias[col];
        float s = 0.f, q = 0.f;
#pragma unroll
        for (int m = 0; m < 4; ++m) {
#pragma unroll
            for (int j = 0; j < 4; ++j) {
                int row = row0 + wm * 64 + m * 16 + lk * 4 + j;
                if (row < nrows) {
                    float v = acc[m][n][j] + bv;
                    if (OUT_BF)
                        ((unsigned short*)Cout)[(size_t)row * COUT + col] = f2b(v);
                    else
                        ((float*)Cout)[(size_t)row * COUT + col] = v;
                    if (STATS) { s += v; q += v * v; }
                }
            }
        }
        if (STATS) {
            ls1[col_local * 8 + wm * 4 + lk] = s;
            ls2[col_local * 8 + wm * 4 + lk] = q;
        }
    }
    if (STATS) {
        __syncthreads();
        if (t < 64) {
            float ss = 0.f, qq = 0.f;
#pragma unroll
            for (int g = 0; g < 8; ++g) { ss += ls1[t * 8 + g]; qq += ls2[t * 8 + g]; }
            psum[(size_t)blockIdx.x * COUT + col0 + t] = ss;
            psq[(size_t)blockIdx.x * COUT + col0 + t]  = qq;
        }
    }
}

// finalize: one block per channel; psum layout [P][C]
__global__ void k_stats_fin(const float* __restrict__ psum, const float* __restrict__ psq,
                            const float* __restrict__ g, const float* __restrict__ bta,
                            float* __restrict__ scl, float* __restrict__ shf,
                            int nrows, int C, int P) {
    __shared__ float r1[256], r2[256];
    int c = blockIdx.x;
    int t = threadIdx.x;
    float s = 0.f, sq = 0.f;
    for (int b = t; b < P; b += 256) {
        s  += psum[(size_t)b * C + c];
        sq += psq[(size_t)b * C + c];
    }
    r1[t] = s; r2[t] = sq;
    for (int off = 128; off; off >>= 1) {
        __syncthreads();
        if (t < off) { r1[t] += r1[t + off]; r2[t] += r2[t + off]; }
    }
    __syncthreads();
    if (t == 0) {
        float mean = r1[0] / (float)nrows;
        float var  = r2[0] / (float)nrows - mean * mean;
        float is   = rsqrtf(var + BNEPS);
        float sc   = g[c] * is;
        scl[c] = sc;
        shf[c] = bta[c] - mean * sc;
    }
}

// ---------------- residual (x4 vectorized): h = maybe_relu(bn(z)) + h ----------------
__global__ void k_residual(const float* __restrict__ z, const float* __restrict__ scl,
                           const float* __restrict__ shf, float* __restrict__ h,
                           unsigned short* __restrict__ hb, int n, int relu_flag) {
    int idx = blockIdx.x * blockDim.x + threadIdx.x;
    if (idx >= n * (DIM / 4)) return;
    int i = idx * 4;
    int c = i & 127;
    const float4 zv = *(const float4*)(z + i);
    const float4 sv = *(const float4*)(scl + c);
    const float4 fv = *(const float4*)(shf + c);
    float4 hv = *(const float4*)(h + i);
    float v0 = zv.x * sv.x + fv.x;
    float v1 = zv.y * sv.y + fv.y;
    float v2 = zv.z * sv.z + fv.z;
    float v3 = zv.w * sv.w + fv.w;
    if (relu_flag) { v0 = relu_(v0); v1 = relu_(v1); v2 = relu_(v2); v3 = relu_(v3); }
    float4 o;
    o.x = v0 + hv.x; o.y = v1 + hv.y; o.z = v2 + hv.z; o.w = v3 + hv.w;
    *(float4*)(h + i) = o;
    if (hb) {
        uint2 ob;
        ob.x = pk(o.x, o.y);
        ob.y = pk(o.z, o.w);
        *(uint2*)(hb + i) = ob;
    }
}

// ---------------- gate ----------------
__global__ __launch_bounds__(256) void k_gate(
    const float* __restrict__ t1, const float* __restrict__ scl, const float* __restrict__ shf,
    const float* __restrict__ W2, const float* __restrict__ b2,
    const float* __restrict__ gumbels, float* __restrict__ gate, int n) {
    __shared__ float w0[256], w1[256];
    int t = threadIdx.x;
    w0[t] = W2[t * 2];
    w1[t] = W2[t * 2 + 1];
    __syncthreads();
    int wv = t >> 6, lane = t & 63;
    int node = blockIdx.x * 4 + wv;
    if (node >= n) return;
    int c = lane << 2;
    const float4 v = *(const float4*)(t1 + (size_t)node * 256 + c);
    float a0 = 0.f, a1 = 0.f;
    float tv;
    tv = relu_(v.x * scl[c + 0] + shf[c + 0]); a0 += tv * w0[c + 0]; a1 += tv * w1[c + 0];
    tv = relu_(v.y * scl[c + 1] + shf[c + 1]); a0 += tv * w0[c + 1]; a1 += tv * w1[c + 1];
    tv = relu_(v.z * scl[c + 2] + shf[c + 2]); a0 += tv * w0[c + 2]; a1 += tv * w1[c + 2];
    tv = relu_(v.w * scl[c + 3] + shf[c + 3]); a0 += tv * w0[c + 3]; a1 += tv * w1[c + 3];
    for (int off = 32; off; off >>= 1) {
        a0 += __shfl_down(a0, off);
        a1 += __shfl_down(a1, off);
    }
    if (lane == 0) {
        float l0 = a0 + b2[0] + gumbels[(size_t)node * 2 + 0];
        float l1 = a1 + b2[1] + gumbels[(size_t)node * 2 + 1];
        gate[node] = (l1 > l0) ? 1.f : 0.f;
    }
}

// ---------------- per-graph reduction ----------------
__global__ void k_segreduce(const float* __restrict__ h, const float* __restrict__ gate,
                            const int* __restrict__ gptr, float* __restrict__ hr,
                            float* __restrict__ lossg, int B) {
    __shared__ float red[256];
    int g = blockIdx.x, t = threadIdx.x;
    int beg = gptr[g], end = gptr[g + 1];
    int cnt = end - beg;
    float gs = 0.f;
    for (int nrow = beg + t; nrow < end; nrow += 256) gs += gate[nrow];
    red[t] = gs;
    for (int off = 128; off; off >>= 1) {
        __syncthreads();
        if (t < off) red[t] += red[t + off];
    }
    __syncthreads();
    float rnum = red[0];
    __syncthreads();
    if (t == 0) {
        float r = rnum + 1e-8f;
        float e = ((float)cnt - rnum) + 1e-8f;
        lossg[g] = fabsf(r / (r + e) - GAMMA_);
    }
    int c = t & 127, rs = t >> 7;
    float acc = 0.f;
    for (int nrow = beg + rs; nrow < end; nrow += 2) {
        float gt = gate[nrow];
        if (gt != 0.f) acc += h[(size_t)nrow * 128 + c];
    }
    red[t] = acc;
    __syncthreads();
    if (rs == 0) {
        float tot = red[t] + red[t + 128];
        hr[(size_t)g * 128 + c] = tot / fmaxf((float)cnt, 1.f);
    }
}

__global__ void k_loss(const float* __restrict__ lossg, float* __restrict__ out, int B) {
    __shared__ float red[256];
    int t = threadIdx.x;
    float s = 0.f;
    for (int g = t; g < B; g += 256) s += lossg[g];
    red[t] = s;
    for (int off = 128; off; off >>= 1) {
        __syncthreads();
        if (t < off) red[t] += red[t + off];
    }
    __syncthreads();
    if (t == 0) out[NGRAPH * NTASK] = red[0] / (float)B;
}

// ---------------- pred head final ----------------
__global__ void k_pred_out(const float* __restrict__ tp, const float* __restrict__ scl,
                           const float* __restrict__ shf, const float* __restrict__ W2,
                           const float* __restrict__ b2, float* __restrict__ out, int B) {
    int i = blockIdx.x * blockDim.x + threadIdx.x;
    if (i >= B * NTASK) return;
    int g = i / NTASK, j = i % NTASK;
    float acc = b2[j];
    for (int k = 0; k < 256; ++k) {
        float v = relu_(tp[(size_t)g * 256 + k] * scl[k] + shf[k]);
        acc += v * W2[k * NTASK + j];
    }
    out[i] = acc;
}

extern "C" void kernel_launch(void* const* d_in, const int* in_sizes, int n_in,
                              void* d_out, int out_size, void* d_ws, size_t ws_size,
                              hipStream_t stream) {
    const float* x       = (const float*)d_in[0];
    const int*   eidx    = (const int*)d_in[1];
    const int*   eattr   = (const int*)d_in[2];
    const int*   batch   = (const int*)d_in[3];
    const float* gumbels = (const float*)d_in[5];
    const float* node_W  = (const float*)d_in[6];
    const float* node_b  = (const float*)d_in[7];
    const float* enc_eps = (const float*)d_in[8];
    const float* enc_edge= (const float*)d_in[9];
    const float* enc_W1  = (const float*)d_in[10];
    const float* enc_b1  = (const float*)d_in[11];
    const float* enc_bn1g= (const float*)d_in[12];
    const float* enc_bn1b= (const float*)d_in[13];
    const float* enc_W2  = (const float*)d_in[14];
    const float* enc_b2  = (const float*)d_in[15];
    const float* enc_bng = (const float*)d_in[16];
    const float* enc_bnb = (const float*)d_in[17];
    const float* rat_eps = (const float*)d_in[18];
    const float* rat_edge= (const float*)d_in[19];
    const float* rat_W1  = (const float*)d_in[20];
    const float* rat_b1  = (const float*)d_in[21];
    const float* rat_bn1g= (const float*)d_in[22];
    const float* rat_bn1b= (const float*)d_in[23];
    const float* rat_W2  = (const float*)d_in[24];
    const float* rat_b2  = (const float*)d_in[25];
    const float* rat_bng = (const float*)d_in[26];
    const float* rat_bnb = (const float*)d_in[27];
    const float* gate_W1 = (const float*)d_in[28];
    const float* gate_b1 = (const float*)d_in[29];
    const float* gate_bng= (const float*)d_in[30];
    const float* gate_bnb= (const float*)d_in[31];
    const float* gate_W2 = (const float*)d_in[32];
    const float* gate_b2 = (const float*)d_in[33];
    const float* pred_W1 = (const float*)d_in[34];
    const float* pred_b1 = (const float*)d_in[35];
    const float* pred_bng= (const float*)d_in[36];
    const float* pred_bnb= (const float*)d_in[37];
    const float* pred_W2 = (const float*)d_in[38];
    const float* pred_b2 = (const float*)d_in[39];
    float* out = (float*)d_out;

    const int N = in_sizes[0] / 4;
    const int E = in_sizes[2];
    const int B = NGRAPH;

    const int gM64  = (N + 63) / 64;
    const int gM128 = (N + 127) / 128;

    // workspace carve
    char* w = (char*)d_ws;
    auto alloc = [&](size_t bytes) {
        char* p = w;
        w += (bytes + 255) & ~(size_t)255;
        return p;
    };
    float* h     = (float*)alloc((size_t)N * DIM * 4);
    float* buf   = (float*)alloc((size_t)N * DIM * 4);
    char*  t1base= alloc((size_t)N * DIM2 * 4);
    float* gate  = (float*)alloc((size_t)N * 4);
    float* scl   = (float*)alloc(256 * 4);
    float* shf   = (float*)alloc(256 * 4);
    float* psum  = (float*)alloc((size_t)gM64 * 256 * 4);
    float* psq   = (float*)alloc((size_t)gM64 * 256 * 4);
    float* hr    = (float*)alloc((size_t)B * DIM * 4);
    float* tpred = (float*)alloc((size_t)B * DIM2 * 4);
    float* lossg = (float*)alloc((size_t)B * 4);
    int* deg     = (int*)alloc((size_t)N * 4);
    int* incl    = (int*)alloc((size_t)N * 4);
    int* cursor  = (int*)alloc((size_t)N * 4);
    int* rowptr  = (int*)alloc((size_t)(N + 1) * 4);
    int* bsum    = (int*)alloc(128 * 4);
    int* boff    = (int*)alloc(128 * 4);
    int* srcs    = (int*)alloc((size_t)E * 4);
    int* eas     = (int*)alloc((size_t)E * 4);
    int* gptr    = (int*)alloc((size_t)(B + 1) * 4);
    unsigned short* W1t = (unsigned short*)alloc((size_t)5 * DIM2 * DIM * 2);
    unsigned short* W2t = (unsigned short*)alloc((size_t)5 * DIM * DIM2 * 2);

    // t1 fp32 region (rationale/gate phase) aliased by encoder bf16 buffers:
    float* t1          = (float*)t1base;
    unsigned short* zb  = (unsigned short*)t1base;
    unsigned short* t1b = (unsigned short*)(t1base + (size_t)N * DIM * 2);
    unsigned short* hb  = (unsigned short*)(t1base + (size_t)N * (DIM + DIM2) * 2);

    const int NB = (N + 1023) / 1024;

    // ---- CSR build (by dst) ----
    hipMemsetAsync(deg, 0, (size_t)N * 4, stream);
    k_count_deg<<<(E + 255) / 256, 256, 0, stream>>>(eidx + E, deg, E);
    k_scan_block<<<NB, 1024, 0, stream>>>(deg, incl, bsum, N);
    k_scan_bsum<<<1, 128, 0, stream>>>(bsum, boff, NB);
    k_scan_final<<<(N + 255) / 256, 256, 0, stream>>>(incl, deg, boff, rowptr, cursor, N);
    k_fill_csr<<<(E + 255) / 256, 256, 0, stream>>>(eidx, eidx + E, eattr, cursor, srcs, eas, E);
    k_graph_ptr<<<(B + 256) / 256, 256, 0, stream>>>(batch, gptr, N, B);

    // ---- encoder weight conversion (transposed bf16) ----
    {
        long long tot1 = 5LL * DIM * DIM2;
        k_wconv<<<(int)((tot1 + 255) / 256), 256, 0, stream>>>(enc_W1, W1t, 5, DIM, DIM2);
        k_wconv<<<(int)((tot1 + 255) / 256), 256, 0, stream>>>(enc_W2, W2t, 5, DIM2, DIM);
    }

    const int gE4 = (N * (DIM / 4) + 255) / 256;

    // ---- rationale stack (fp32, fused stats) + gate ----
    k_h0<<<gE4, 256, 0, stream>>>(x, node_W, node_b, h, nullptr, N);
    for (int l = 0; l < 2; ++l) {
        k_aggregate<<<(N + 7) / 8, 256, 0, stream>>>(h, rowptr, srcs, eas, rat_edge, rat_eps, l, buf, N);
        k_mmf<128, 256, false, true><<<dim3(gM64, 2), 256, 0, stream>>>(
            buf, rat_W1 + (size_t)l * 128 * 256, rat_b1 + (size_t)l * 256, nullptr, nullptr,
            t1, psum, psq, N);
        k_stats_fin<<<256, 256, 0, stream>>>(psum, psq, rat_bn1g + (size_t)l * 256,
                                             rat_bn1b + (size_t)l * 256, scl, shf, N, 256, gM64);
        k_mmf<256, 128, true, true><<<dim3(gM64, 1), 256, 0, stream>>>(
            t1, rat_W2 + (size_t)l * 256 * 128, rat_b2 + (size_t)l * 128, scl, shf,
            buf, psum, psq, N);
        k_stats_fin<<<128, 256, 0, stream>>>(psum, psq, rat_bng + (size_t)l * 128,
                                             rat_bnb + (size_t)l * 128, scl, shf, N, 128, gM64);
        k_residual<<<gE4, 256, 0, stream>>>(buf, scl, shf, h, nullptr, N, (l < 1) ? 1 : 0);
    }
    k_mmf<128, 256, false, true><<<dim3(gM64, 2), 256, 0, stream>>>(
        h, gate_W1, gate_b1, nullptr, nullptr, t1, psum, psq, N);
    k_stats_fin<<<256, 256, 0, stream>>>(psum, psq, gate_bng, gate_bnb, scl, shf, N, 256, gM64);
    k_gate<<<(N + 3) / 4, 256, 0, stream>>>(t1, scl, shf, gate_W2, gate_b2, gumbels, gate, N);

    // ---- encoder stack (bf16 MFMA, fused stats) ----
    k_h0<<<gE4, 256, 0, stream>>>(x, node_W, node_b, h, hb, N);
    for (int l = 0; l < 5; ++l) {
        k_agg_bf<<<(N + 7) / 8, 256, 0, stream>>>(hb, rowptr, srcs, eas, enc_edge, enc_eps, l, zb, N);
        k_mm_bf<128, 256, false, true, true><<<dim3(gM128, 4), 256, 0, stream>>>(
            zb, W1t + (size_t)l * DIM2 * DIM, enc_b1 + (size_t)l * 256, nullptr, nullptr,
            t1b, psum, psq, N);
        k_stats_fin<<<256, 256, 0, stream>>>(psum, psq, enc_bn1g + (size_t)l * 256,
                                             enc_bn1b + (size_t)l * 256, scl, shf, N, 256, gM128);
        k_mm_bf<256, 128, true, false, true><<<dim3(gM128, 2), 256, 0, stream>>>(
            t1b, W2t + (size_t)l * DIM * DIM2, enc_b2 + (size_t)l * 128, scl, shf,
            buf, psum, psq, N);
        k_stats_fin<<<128, 256, 0, stream>>>(psum, psq, enc_bng + (size_t)l * 128,
                                             enc_bnb + (size_t)l * 128, scl, shf, N, 128, gM128);
        k_residual<<<gE4, 256, 0, stream>>>(buf, scl, shf, h, (l < 4) ? hb : nullptr, N, (l < 4) ? 1 : 0);
    }

    // ---- per-graph reductions + loss ----
    k_segreduce<<<B, 256, 0, stream>>>(h, gate, gptr, hr, lossg, B);
    k_loss<<<1, 256, 0, stream>>>(lossg, out, B);

    // ---- pred head (fp32, fused stats) ----
    {
        const int gMB = (B + 63) / 64;
        k_mmf<128, 256, false, true><<<dim3(gMB, 2), 256, 0, stream>>>(
            hr, pred_W1, pred_b1, nullptr, nullptr, tpred, psum, psq, B);
        k_stats_fin<<<256, 256, 0, stream>>>(psum, psq, pred_bng, pred_bnb, scl, shf, B, 256, gMB);
        k_pred_out<<<(B * NTASK + 255) / 256, 256, 0, stream>>>(tpred, scl, shf, pred_W2,
                                                                pred_b2, out, B);
    }
}

// Round 15
// 1650.101 us; speedup vs baseline: 1.0186x; 1.0186x over previous
//
#include <hip/hip_runtime.h>
#include <cstddef>

#define DIM    128
#define DIM2   256
#define NGRAPH 1024
#define NTASK  10
#define NEV    4
#define BNEPS  1e-5f
#define GAMMA_ 0.4f

typedef __attribute__((ext_vector_type(2))) float f32x2;
typedef __attribute__((ext_vector_type(4))) float f32x4;
typedef __attribute__((ext_vector_type(8))) short s16x8;

static __device__ __forceinline__ float relu_(float v) { return v > 0.f ? v : 0.f; }
static __device__ __forceinline__ unsigned short f2b(float f) {
    unsigned int u = __float_as_uint(f);
    unsigned int r = (u + 0x7fffu + ((u >> 16) & 1u)) >> 16;
    return (unsigned short)r;
}
static __device__ __forceinline__ float b2f(unsigned short b) {
    return __uint_as_float(((unsigned int)b) << 16);
}
static __device__ __forceinline__ unsigned int pk(float a, float b) {
    return (unsigned int)f2b(a) | ((unsigned int)f2b(b) << 16);
}

// ---------------- CSR build ----------------
__global__ void k_count_deg(const int* __restrict__ dst, int* __restrict__ deg, int E) {
    int e = blockIdx.x * blockDim.x + threadIdx.x;
    if (e < E) atomicAdd(&deg[dst[e]], 1);
}

__global__ void k_scan_block(const int* __restrict__ deg, int* __restrict__ incl,
                             int* __restrict__ bsum, int n) {
    __shared__ int s[1024];
    int i = blockIdx.x * 1024 + threadIdx.x;
    int v = (i < n) ? deg[i] : 0;
    s[threadIdx.x] = v;
    __syncthreads();
    for (int off = 1; off < 1024; off <<= 1) {
        int t = (threadIdx.x >= off) ? s[threadIdx.x - off] : 0;
        __syncthreads();
        s[threadIdx.x] += t;
        __syncthreads();
    }
    if (i < n) incl[i] = s[threadIdx.x];
    if (threadIdx.x == 1023) bsum[blockIdx.x] = s[1023];
}

__global__ void k_scan_bsum(const int* __restrict__ bsum, int* __restrict__ boff, int nb) {
    __shared__ int s[128];
    int t = threadIdx.x;
    s[t] = (t < nb) ? bsum[t] : 0;
    __syncthreads();
    for (int off = 1; off < 128; off <<= 1) {
        int v = (t >= off) ? s[t - off] : 0;
        __syncthreads();
        s[t] += v;
        __syncthreads();
    }
    if (t < nb) boff[t] = (t == 0) ? 0 : s[t - 1];
}

__global__ void k_scan_final(const int* __restrict__ incl, const int* __restrict__ deg,
                             const int* __restrict__ boff, int* __restrict__ rowptr,
                             int* __restrict__ cursor, int n) {
    int i = blockIdx.x * blockDim.x + threadIdx.x;
    if (i < n) {
        int v = incl[i] + boff[i >> 10];
        rowptr[i + 1] = v;
        cursor[i] = v - deg[i];
    }
    if (i == 0) rowptr[0] = 0;
}

__global__ void k_fill_csr(const int* __restrict__ src, const int* __restrict__ dst,
                           const int* __restrict__ ea, int* __restrict__ cursor,
                           int* __restrict__ src_s, int* __restrict__ ea_s, int E) {
    int e = blockIdx.x * blockDim.x + threadIdx.x;
    if (e < E) {
        int p = atomicAdd(&cursor[dst[e]], 1);
        src_s[p] = src[e];
        ea_s[p]  = ea[e];
    }
}

__global__ void k_graph_ptr(const int* __restrict__ batch, int* __restrict__ gptr, int n, int B) {
    int g = blockIdx.x * blockDim.x + threadIdx.x;
    if (g > B) return;
    int lo = 0, hi = n;
    while (lo < hi) {
        int mid = (lo + hi) >> 1;
        if (batch[mid] < g) lo = mid + 1; else hi = mid;
    }
    gptr[g] = lo;
}

// ---------------- weight convert: Wt[l][c][k] = bf16(W[l][k][c]) ----------------
__global__ void k_wconv(const float* __restrict__ W, unsigned short* __restrict__ Wt,
                        int L, int K, int COUT) {
    long long i = (long long)blockIdx.x * 256 + threadIdx.x;
    long long total = (long long)L * K * COUT;
    if (i >= total) return;
    int l = (int)(i / (K * COUT));
    int rem = (int)(i % (K * COUT));
    int c = rem / K, k = rem % K;
    Wt[i] = f2b(W[(size_t)l * K * COUT + (size_t)k * COUT + c]);
}

// ---------------- node init (x4 vectorized) ----------------
__global__ void k_h0(const float* __restrict__ x, const float* __restrict__ W,
                     const float* __restrict__ b, float* __restrict__ h,
                     unsigned short* __restrict__ hb, int n) {
    int idx = blockIdx.x * blockDim.x + threadIdx.x;
    if (idx >= n * (DIM / 4)) return;
    int node = idx >> 5;
    int c4 = (idx & 31) << 2;
    const float* xr = x + (size_t)node * 4;
    float x0 = xr[0], x1 = xr[1], x2 = xr[2], x3 = xr[3];
    const float4 w0 = *(const float4*)(W + c4);
    const float4 w1 = *(const float4*)(W + DIM + c4);
    const float4 w2 = *(const float4*)(W + 2 * DIM + c4);
    const float4 w3 = *(const float4*)(W + 3 * DIM + c4);
    const float4 bv = *(const float4*)(b + c4);
    float4 o;
    o.x = bv.x + x0 * w0.x + x1 * w1.x + x2 * w2.x + x3 * w3.x;
    o.y = bv.y + x0 * w0.y + x1 * w1.y + x2 * w2.y + x3 * w3.y;
    o.z = bv.z + x0 * w0.z + x1 * w1.z + x2 * w2.z + x3 * w3.z;
    o.w = bv.w + x0 * w0.w + x1 * w1.w + x2 * w2.w + x3 * w3.w;
    size_t off = (size_t)node * DIM + c4;
    *(float4*)(h + off) = o;
    if (hb) {
        uint2 ob;
        ob.x = pk(o.x, o.y);
        ob.y = pk(o.z, o.w);
        *(uint2*)(hb + off) = ob;
    }
}

// ---------------- edge aggregation, fp32 h -> fp32 z (4-edge unrolled) ----------------
__global__ __launch_bounds__(256) void k_aggregate(
    const float* __restrict__ h, const int* __restrict__ rowptr,
    const int* __restrict__ src_s, const int* __restrict__ ea_s,
    const float* __restrict__ emb, const float* __restrict__ eps_arr, int l,
    float* __restrict__ zout, int n) {
    __shared__ float semb[NEV * DIM];
    int t = threadIdx.x;
    for (int i = t; i < NEV * DIM; i += 256) semb[i] = emb[(size_t)l * NEV * DIM + i];
    __syncthreads();
    int grp = t >> 5, lane = t & 31;
    int node = blockIdx.x * 8 + grp;
    if (node >= n) return;
    float eps1 = 1.0f + eps_arr[l];
    int beg = rowptr[node], end = rowptr[node + 1];
    int c = lane << 2;
    float4 acc = {0.f, 0.f, 0.f, 0.f};
    int e = beg;
    for (; e + 4 <= end; e += 4) {
        int s0 = src_s[e], s1 = src_s[e + 1], s2 = src_s[e + 2], s3 = src_s[e + 3];
        int a0 = ea_s[e], a1 = ea_s[e + 1], a2 = ea_s[e + 2], a3 = ea_s[e + 3];
        const float4 hv0 = *(const float4*)(h + (size_t)s0 * DIM + c);
        const float4 hv1 = *(const float4*)(h + (size_t)s1 * DIM + c);
        const float4 hv2 = *(const float4*)(h + (size_t)s2 * DIM + c);
        const float4 hv3 = *(const float4*)(h + (size_t)s3 * DIM + c);
        const float4 ev0 = *(const float4*)(semb + a0 * DIM + c);
        const float4 ev1 = *(const float4*)(semb + a1 * DIM + c);
        const float4 ev2 = *(const float4*)(semb + a2 * DIM + c);
        const float4 ev3 = *(const float4*)(semb + a3 * DIM + c);
        acc.x += relu_(hv0.x + ev0.x); acc.y += relu_(hv0.y + ev0.y);
        acc.z += relu_(hv0.z + ev0.z); acc.w += relu_(hv0.w + ev0.w);
        acc.x += relu_(hv1.x + ev1.x); acc.y += relu_(hv1.y + ev1.y);
        acc.z += relu_(hv1.z + ev1.z); acc.w += relu_(hv1.w + ev1.w);
        acc.x += relu_(hv2.x + ev2.x); acc.y += relu_(hv2.y + ev2.y);
        acc.z += relu_(hv2.z + ev2.z); acc.w += relu_(hv2.w + ev2.w);
        acc.x += relu_(hv3.x + ev3.x); acc.y += relu_(hv3.y + ev3.y);
        acc.z += relu_(hv3.z + ev3.z); acc.w += relu_(hv3.w + ev3.w);
    }
    for (; e < end; ++e) {
        int s = src_s[e];
        int a = ea_s[e];
        const float4 hv = *(const float4*)(h + (size_t)s * DIM + c);
        const float4 ev = *(const float4*)(semb + a * DIM + c);
        acc.x += relu_(hv.x + ev.x);
        acc.y += relu_(hv.y + ev.y);
        acc.z += relu_(hv.z + ev.z);
        acc.w += relu_(hv.w + ev.w);
    }
    const float4 hn = *(const float4*)(h + (size_t)node * DIM + c);
    float4 o;
    o.x = eps1 * hn.x + acc.x;
    o.y = eps1 * hn.y + acc.y;
    o.z = eps1 * hn.z + acc.z;
    o.w = eps1 * hn.w + acc.w;
    *(float4*)(zout + (size_t)node * DIM + c) = o;
}

// ---------------- edge aggregation, bf16 h -> bf16 z (4-edge unrolled) ----------------
__global__ __launch_bounds__(256) void k_agg_bf(
    const unsigned short* __restrict__ hb, const int* __restrict__ rowptr,
    const int* __restrict__ src_s, const int* __restrict__ ea_s,
    const float* __restrict__ emb, const float* __restrict__ eps_arr, int l,
    unsigned short* __restrict__ zb, int n) {
    __shared__ float semb[NEV * DIM];
    int t = threadIdx.x;
    for (int i = t; i < NEV * DIM; i += 256) semb[i] = emb[(size_t)l * NEV * DIM + i];
    __syncthreads();
    int grp = t >> 5, lane = t & 31;
    int node = blockIdx.x * 8 + grp;
    if (node >= n) return;
    float eps1 = 1.0f + eps_arr[l];
    int beg = rowptr[node], end = rowptr[node + 1];
    int c = lane << 2;
    float ax = 0.f, ay = 0.f, az = 0.f, aw = 0.f;
    int e = beg;
    for (; e + 4 <= end; e += 4) {
        int s0 = src_s[e], s1 = src_s[e + 1], s2 = src_s[e + 2], s3 = src_s[e + 3];
        int a0 = ea_s[e], a1 = ea_s[e + 1], a2 = ea_s[e + 2], a3 = ea_s[e + 3];
        ushort4 hv0 = *(const ushort4*)(hb + (size_t)s0 * DIM + c);
        ushort4 hv1 = *(const ushort4*)(hb + (size_t)s1 * DIM + c);
        ushort4 hv2 = *(const ushort4*)(hb + (size_t)s2 * DIM + c);
        ushort4 hv3 = *(const ushort4*)(hb + (size_t)s3 * DIM + c);
        const float4 ev0 = *(const float4*)(semb + a0 * DIM + c);
        const float4 ev1 = *(const float4*)(semb + a1 * DIM + c);
        const float4 ev2 = *(const float4*)(semb + a2 * DIM + c);
        const float4 ev3 = *(const float4*)(semb + a3 * DIM + c);
        ax += relu_(b2f(hv0.x) + ev0.x); ay += relu_(b2f(hv0.y) + ev0.y);
        az += relu_(b2f(hv0.z) + ev0.z); aw += relu_(b2f(hv0.w) + ev0.w);
        ax += relu_(b2f(hv1.x) + ev1.x); ay += relu_(b2f(hv1.y) + ev1.y);
        az += relu_(b2f(hv1.z) + ev1.z); aw += relu_(b2f(hv1.w) + ev1.w);
        ax += relu_(b2f(hv2.x) + ev2.x); ay += relu_(b2f(hv2.y) + ev2.y);
        az += relu_(b2f(hv2.z) + ev2.z); aw += relu_(b2f(hv2.w) + ev2.w);
        ax += relu_(b2f(hv3.x) + ev3.x); ay += relu_(b2f(hv3.y) + ev3.y);
        az += relu_(b2f(hv3.z) + ev3.z); aw += relu_(b2f(hv3.w) + ev3.w);
    }
    for (; e < end; ++e) {
        int s = src_s[e];
        int a = ea_s[e];
        ushort4 hv = *(const ushort4*)(hb + (size_t)s * DIM + c);
        const float4 ev = *(const float4*)(semb + a * DIM + c);
        ax += relu_(b2f(hv.x) + ev.x);
        ay += relu_(b2f(hv.y) + ev.y);
        az += relu_(b2f(hv.z) + ev.z);
        aw += relu_(b2f(hv.w) + ev.w);
    }
    ushort4 hn = *(const ushort4*)(hb + (size_t)node * DIM + c);
    uint2 o;
    o.x = pk(eps1 * b2f(hn.x) + ax, eps1 * b2f(hn.y) + ay);
    o.y = pk(eps1 * b2f(hn.z) + az, eps1 * b2f(hn.w) + aw);
    *(uint2*)(zb + (size_t)node * DIM + c) = o;
}

// ---------------- fp32 tiled matmul + fused BN-stats epilogue ----------------
// 64x128 tile, BK=32, thread 4x(4+4); gload staging (W linear, A chunk-XOR swizzled).
template <int K, int COUT, bool TRANS, bool STATS>
__global__ __launch_bounds__(256) void k_mmf(
    const float* __restrict__ A, const float* __restrict__ W,
    const float* __restrict__ bias, const float* __restrict__ scl,
    const float* __restrict__ shf, float* __restrict__ C,
    float* __restrict__ psum, float* __restrict__ psq, int nrows) {
    __shared__ float Asl[64 * 32];    // 8 KB, swizzled
    __shared__ float Wsl[32 * 128];   // 16 KB, linear
    const int t = threadIdx.x;
    const int lane = t & 63, wid = t >> 6;
    const int row0 = blockIdx.x * 64;
    const int col0 = blockIdx.y * 128;
    const int tc = t & 15;
    const int tr = t >> 4;
    f32x4 acc[4][2] = {};
    for (int k0 = 0; k0 < K; k0 += 32) {
        if (!TRANS) {
#pragma unroll
            for (int i = 0; i < 2; ++i) {
                int g = i * 4 + wid;
                int s = g * 64 + lane;
                int r = s >> 3, c = s & 7;
                int gr = row0 + r; if (gr >= nrows) gr = nrows - 1;
                int cs = c ^ ((r & 7) ^ ((r >> 3) & 7));
                const float* src = A + (size_t)gr * K + k0 + (cs << 2);
                __builtin_amdgcn_global_load_lds((const unsigned int*)src,
                    (unsigned int*)((char*)Asl + g * 1024), 16, 0, 0);
            }
        } else {
#pragma unroll
            for (int j = 0; j < 2; ++j) {
                int ff = j * 256 + t;
                int r = ff >> 3;
                int kc = (ff & 7) << 2;
                int grow = row0 + r;
                float4 v = {0.f, 0.f, 0.f, 0.f};
                if (grow < nrows) {
                    v = *(const float4*)(A + (size_t)grow * K + (k0 + kc));
                    const float4 s4 = *(const float4*)(scl + k0 + kc);
                    const float4 h4 = *(const float4*)(shf + k0 + kc);
                    v.x = relu_(v.x * s4.x + h4.x);
                    v.y = relu_(v.y * s4.y + h4.y);
                    v.z = relu_(v.z * s4.z + h4.z);
                    v.w = relu_(v.w * s4.w + h4.w);
                }
                int byte = (r * 128 + kc * 4) ^ ((((r & 7) ^ ((r >> 3) & 7))) << 4);
                *(float4*)((char*)Asl + byte) = v;
            }
        }
#pragma unroll
        for (int i = 0; i < 4; ++i) {
            int g = i * 4 + wid;
            int s = g * 64 + lane;
            int kr = s >> 5, c = s & 31;
            const float* src = W + (size_t)(k0 + kr) * COUT + col0 + (c << 2);
            __builtin_amdgcn_global_load_lds((const unsigned int*)src,
                (unsigned int*)((char*)Wsl + g * 1024), 16, 0, 0);
        }
        __syncthreads();
#pragma unroll
        for (int k4 = 0; k4 < 32; k4 += 4) {
            f32x4 a4[4];
#pragma unroll
            for (int r = 0; r < 4; ++r) {
                int row = (tr << 2) + r;
                int byte = (row * 128 + k4 * 4) ^ ((((row & 7) ^ ((row >> 3) & 7))) << 4);
                a4[r] = *(const f32x4*)((const char*)Asl + byte);
            }
#pragma unroll
            for (int kk = 0; kk < 4; ++kk) {
                const f32x4 w0 = *(const f32x4*)(Wsl + (k4 + kk) * 128 + (tc << 2));
                const f32x4 w1 = *(const f32x4*)(Wsl + (k4 + kk) * 128 + 64 + (tc << 2));
#pragma unroll
                for (int r = 0; r < 4; ++r) {
                    float a = a4[r][kk];
                    f32x4 av = {a, a, a, a};
                    acc[r][0] = __builtin_elementwise_fma(av, w0, acc[r][0]);
                    acc[r][1] = __builtin_elementwise_fma(av, w1, acc[r][1]);
                }
            }
        }
        __syncthreads();
    }
    const f32x4 b0 = *(const f32x4*)(bias + col0 + (tc << 2));
    const f32x4 b1 = *(const f32x4*)(bias + col0 + 64 + (tc << 2));
    float s0[4] = {}, q0[4] = {}, s1[4] = {}, q1[4] = {};
#pragma unroll
    for (int r = 0; r < 4; ++r) {
        int row = row0 + (tr << 2) + r;
        if (row < nrows) {
            f32x4 o0 = acc[r][0] + b0;
            f32x4 o1 = acc[r][1] + b1;
            *(f32x4*)(C + (size_t)row * COUT + col0 + (tc << 2)) = o0;
            *(f32x4*)(C + (size_t)row * COUT + col0 + 64 + (tc << 2)) = o1;
            if (STATS) {
#pragma unroll
                for (int j = 0; j < 4; ++j) {
                    s0[j] += o0[j]; q0[j] += o0[j] * o0[j];
                    s1[j] += o1[j]; q1[j] += o1[j] * o1[j];
                }
            }
        }
    }
    if (STATS) {
        float* ls1 = Wsl;   // 16 x 128
        float* ls2 = Asl;   // 16 x 128
        __syncthreads();
#pragma unroll
        for (int j = 0; j < 4; ++j) {
            ls1[tr * 128 + (tc << 2) + j] = s0[j];
            ls1[tr * 128 + 64 + (tc << 2) + j] = s1[j];
            ls2[tr * 128 + (tc << 2) + j] = q0[j];
            ls2[tr * 128 + 64 + (tc << 2) + j] = q1[j];
        }
        __syncthreads();
        if (t < 128) {
            float ss = 0.f, qq = 0.f;
#pragma unroll
            for (int g = 0; g < 16; ++g) { ss += ls1[g * 128 + t]; qq += ls2[g * 128 + t]; }
            psum[(size_t)blockIdx.x * COUT + col0 + t] = ss;
            psq[(size_t)blockIdx.x * COUT + col0 + t]  = qq;
        }
    }
}

// ---------------- bf16 MFMA matmul (encoder) + fused BN-stats ----------------
// 128x64 tile, BK=64, 4 waves, wave tile 64x32, acc 4x2; gload staging.
template <int K, int COUT, bool TRANS, bool OUT_BF, bool STATS>
__global__ __launch_bounds__(256) void k_mm_bf(
    const unsigned short* __restrict__ A, const unsigned short* __restrict__ Wt,
    const float* __restrict__ bias, const float* __restrict__ scl,
    const float* __restrict__ shf, void* __restrict__ Cout,
    float* __restrict__ psum, float* __restrict__ psq, int nrows) {
    __shared__ unsigned short As[128 * 64];  // row-major, XOR-swizzled
    __shared__ unsigned short Bs[64 * 64];   // Bt[col][k], XOR-swizzled
    const int t = threadIdx.x;
    const int row0 = blockIdx.x * 128;
    const int col0 = blockIdx.y * 64;
    const int wid = t >> 6, lane = t & 63;
    const int wm = wid & 1, wn = wid >> 1;
    const int lr = lane & 15, lk = lane >> 4;
    f32x4 acc[4][2] = {};
    for (int k0 = 0; k0 < K; k0 += 64) {
        // ---- stage A (128 rows x 64 k bf16) ----
        if (!TRANS) {
#pragma unroll
            for (int i = 0; i < 4; ++i) {
                int g = i * 4 + wid;
                int s = g * 64 + lane;
                int r = s >> 3, c = s & 7;
                int gr = row0 + r; if (gr >= nrows) gr = nrows - 1;
                int cs = c ^ (r & 7);
                const unsigned short* src = A + (size_t)gr * K + k0 + (cs << 3);
                __builtin_amdgcn_global_load_lds((const unsigned int*)src,
                    (unsigned int*)((char*)As + g * 1024), 16, 0, 0);
            }
        } else {
#pragma unroll
            for (int i = 0; i < 4; ++i) {
                int idx = i * 256 + t;
                int r = idx >> 3;
                int kc = (idx & 7) * 8;
                int gr = row0 + r;
                uint4 v = {0u, 0u, 0u, 0u};
                if (gr < nrows) {
                    uint4 raw = *(const uint4*)(A + (size_t)gr * K + k0 + kc);
                    const float4 s0 = *(const float4*)(scl + k0 + kc);
                    const float4 s1 = *(const float4*)(scl + k0 + kc + 4);
                    const float4 h0 = *(const float4*)(shf + k0 + kc);
                    const float4 h1 = *(const float4*)(shf + k0 + kc + 4);
                    float v0 = relu_(b2f((unsigned short)(raw.x & 0xffff)) * s0.x + h0.x);
                    float v1 = relu_(b2f((unsigned short)(raw.x >> 16))    * s0.y + h0.y);
                    float v2 = relu_(b2f((unsigned short)(raw.y & 0xffff)) * s0.z + h0.z);
                    float v3 = relu_(b2f((unsigned short)(raw.y >> 16))    * s0.w + h0.w);
                    float v4 = relu_(b2f((unsigned short)(raw.z & 0xffff)) * s1.x + h1.x);
                    float v5 = relu_(b2f((unsigned short)(raw.z >> 16))    * s1.y + h1.y);
                    float v6 = relu_(b2f((unsigned short)(raw.w & 0xffff)) * s1.z + h1.z);
                    float v7 = relu_(b2f((unsigned short)(raw.w >> 16))    * s1.w + h1.w);
                    v.x = pk(v0, v1); v.y = pk(v2, v3); v.z = pk(v4, v5); v.w = pk(v6, v7);
                }
                int byte = (r * 128 + kc * 2) ^ ((r & 7) << 4);
                *(uint4*)((char*)As + byte) = v;
            }
        }
        // ---- stage B (64 cols x 64 k bf16), gload ----
#pragma unroll
        for (int i = 0; i < 2; ++i) {
            int g = i * 4 + wid;
            int s = g * 64 + lane;
            int c = s >> 3, kc = s & 7;
            int ks = kc ^ (c & 7);
            const unsigned short* src = Wt + (size_t)(col0 + c) * K + k0 + (ks << 3);
            __builtin_amdgcn_global_load_lds((const unsigned int*)src,
                (unsigned int*)((char*)Bs + g * 1024), 16, 0, 0);
        }
        __syncthreads();
#pragma unroll
        for (int kk = 0; kk < 64; kk += 32) {
            s16x8 bfrag[2];
#pragma unroll
            for (int n = 0; n < 2; ++n) {
                int c = wn * 32 + n * 16 + lr;
                int byte = (c * 128 + (kk + lk * 8) * 2) ^ ((c & 7) << 4);
                bfrag[n] = *(const s16x8*)((const char*)Bs + byte);
            }
#pragma unroll
            for (int m = 0; m < 4; ++m) {
                int r = wm * 64 + m * 16 + lr;
                int byte = (r * 128 + (kk + lk * 8) * 2) ^ ((r & 7) << 4);
                s16x8 afrag = *(const s16x8*)((const char*)As + byte);
                acc[m][0] = __builtin_amdgcn_mfma_f32_16x16x32_bf16(afrag, bfrag[0], acc[m][0], 0, 0, 0);
                acc[m][1] = __builtin_amdgcn_mfma_f32_16x16x32_bf16(afrag, bfrag[1], acc[m][1], 0, 0, 0);
            }
        }
        __syncthreads();
    }
    float* ls1 = (float*)&Bs[0];      // 64 cols x 8 slots
    float* ls2 = ls1 + 512;
#pragma unroll
    for (int n = 0; n < 2; ++n) {
        int col_local = wn * 32 + n * 16 + lr;
        int col = col0 + col_local;
        float bv = bias[col];
        float s = 0.f, q = 0.f;
#pragma unroll
        for (int m = 0; m < 4; ++m) {
#pragma unroll
            for (int j = 0; j < 4; ++j) {
                int row = row0 + wm * 64 + m * 16 + lk * 4 + j;
                if (row < nrows) {
                    float v = acc[m][n][j] + bv;
                    if (OUT_BF)
                        ((unsigned short*)Cout)[(size_t)row * COUT + col] = f2b(v);
                    else
                        ((float*)Cout)[(size_t)row * COUT + col] = v;
                    if (STATS) { s += v; q += v * v; }
                }
            }
        }
        if (STATS) {
            ls1[col_local * 8 + wm * 4 + lk] = s;
            ls2[col_local * 8 + wm * 4 + lk] = q;
        }
    }
    if (STATS) {
        __syncthreads();
        if (t < 64) {
            float ss = 0.f, qq = 0.f;
#pragma unroll
            for (int g = 0; g < 8; ++g) { ss += ls1[t * 8 + g]; qq += ls2[t * 8 + g]; }
            psum[(size_t)blockIdx.x * COUT + col0 + t] = ss;
            psq[(size_t)blockIdx.x * COUT + col0 + t]  = qq;
        }
    }
}

// finalize: one block per channel; psum layout [P][C]
__global__ void k_stats_fin(const float* __restrict__ psum, const float* __restrict__ psq,
                            const float* __restrict__ g, const float* __restrict__ bta,
                            float* __restrict__ scl, float* __restrict__ shf,
                            int nrows, int C, int P) {
    __shared__ float r1[256], r2[256];
    int c = blockIdx.x;
    int t = threadIdx.x;
    float s = 0.f, sq = 0.f;
    for (int b = t; b < P; b += 256) {
        s  += psum[(size_t)b * C + c];
        sq += psq[(size_t)b * C + c];
    }
    r1[t] = s; r2[t] = sq;
    for (int off = 128; off; off >>= 1) {
        __syncthreads();
        if (t < off) { r1[t] += r1[t + off]; r2[t] += r2[t + off]; }
    }
    __syncthreads();
    if (t == 0) {
        float mean = r1[0] / (float)nrows;
        float var  = r2[0] / (float)nrows - mean * mean;
        float is   = rsqrtf(var + BNEPS);
        float sc   = g[c] * is;
        scl[c] = sc;
        shf[c] = bta[c] - mean * sc;
    }
}

// ---------------- residual (x4 vectorized): h = maybe_relu(bn(z)) + h ----------------
__global__ void k_residual(const float* __restrict__ z, const float* __restrict__ scl,
                           const float* __restrict__ shf, float* __restrict__ h,
                           unsigned short* __restrict__ hb, int n, int relu_flag) {
    int idx = blockIdx.x * blockDim.x + threadIdx.x;
    if (idx >= n * (DIM / 4)) return;
    int i = idx * 4;
    int c = i & 127;
    const float4 zv = *(const float4*)(z + i);
    const float4 sv = *(const float4*)(scl + c);
    const float4 fv = *(const float4*)(shf + c);
    float4 hv = *(const float4*)(h + i);
    float v0 = zv.x * sv.x + fv.x;
    float v1 = zv.y * sv.y + fv.y;
    float v2 = zv.z * sv.z + fv.z;
    float v3 = zv.w * sv.w + fv.w;
    if (relu_flag) { v0 = relu_(v0); v1 = relu_(v1); v2 = relu_(v2); v3 = relu_(v3); }
    float4 o;
    o.x = v0 + hv.x; o.y = v1 + hv.y; o.z = v2 + hv.z; o.w = v3 + hv.w;
    *(float4*)(h + i) = o;
    if (hb) {
        uint2 ob;
        ob.x = pk(o.x, o.y);
        ob.y = pk(o.z, o.w);
        *(uint2*)(hb + i) = ob;
    }
}

// ---------------- gate ----------------
__global__ __launch_bounds__(256) void k_gate(
    const float* __restrict__ t1, const float* __restrict__ scl, const float* __restrict__ shf,
    const float* __restrict__ W2, const float* __restrict__ b2,
    const float* __restrict__ gumbels, float* __restrict__ gate, int n) {
    __shared__ float w0[256], w1[256];
    int t = threadIdx.x;
    w0[t] = W2[t * 2];
    w1[t] = W2[t * 2 + 1];
    __syncthreads();
    int wv = t >> 6, lane = t & 63;
    int node = blockIdx.x * 4 + wv;
    if (node >= n) return;
    int c = lane << 2;
    const float4 v = *(const float4*)(t1 + (size_t)node * 256 + c);
    float a0 = 0.f, a1 = 0.f;
    float tv;
    tv = relu_(v.x * scl[c + 0] + shf[c + 0]); a0 += tv * w0[c + 0]; a1 += tv * w1[c + 0];
    tv = relu_(v.y * scl[c + 1] + shf[c + 1]); a0 += tv * w0[c + 1]; a1 += tv * w1[c + 1];
    tv = relu_(v.z * scl[c + 2] + shf[c + 2]); a0 += tv * w0[c + 2]; a1 += tv * w1[c + 2];
    tv = relu_(v.w * scl[c + 3] + shf[c + 3]); a0 += tv * w0[c + 3]; a1 += tv * w1[c + 3];
    for (int off = 32; off; off >>= 1) {
        a0 += __shfl_down(a0, off);
        a1 += __shfl_down(a1, off);
    }
    if (lane == 0) {
        float l0 = a0 + b2[0] + gumbels[(size_t)node * 2 + 0];
        float l1 = a1 + b2[1] + gumbels[(size_t)node * 2 + 1];
        gate[node] = (l1 > l0) ? 1.f : 0.f;
    }
}

// ---------------- per-graph reduction ----------------
__global__ void k_segreduce(const float* __restrict__ h, const float* __restrict__ gate,
                            const int* __restrict__ gptr, float* __restrict__ hr,
                            float* __restrict__ lossg, int B) {
    __shared__ float red[256];
    int g = blockIdx.x, t = threadIdx.x;
    int beg = gptr[g], end = gptr[g + 1];
    int cnt = end - beg;
    float gs = 0.f;
    for (int nrow = beg + t; nrow < end; nrow += 256) gs += gate[nrow];
    red[t] = gs;
    for (int off = 128; off; off >>= 1) {
        __syncthreads();
        if (t < off) red[t] += red[t + off];
    }
    __syncthreads();
    float rnum = red[0];
    __syncthreads();
    if (t == 0) {
        float r = rnum + 1e-8f;
        float e = ((float)cnt - rnum) + 1e-8f;
        lossg[g] = fabsf(r / (r + e) - GAMMA_);
    }
    int c = t & 127, rs = t >> 7;
    float acc = 0.f;
    for (int nrow = beg + rs; nrow < end; nrow += 2) {
        float gt = gate[nrow];
        if (gt != 0.f) acc += h[(size_t)nrow * 128 + c];
    }
    red[t] = acc;
    __syncthreads();
    if (rs == 0) {
        float tot = red[t] + red[t + 128];
        hr[(size_t)g * 128 + c] = tot / fmaxf((float)cnt, 1.f);
    }
}

__global__ void k_loss(const float* __restrict__ lossg, float* __restrict__ out, int B) {
    __shared__ float red[256];
    int t = threadIdx.x;
    float s = 0.f;
    for (int g = t; g < B; g += 256) s += lossg[g];
    red[t] = s;
    for (int off = 128; off; off >>= 1) {
        __syncthreads();
        if (t < off) red[t] += red[t + off];
    }
    __syncthreads();
    if (t == 0) out[NGRAPH * NTASK] = red[0] / (float)B;
}

// ---------------- pred head final ----------------
__global__ void k_pred_out(const float* __restrict__ tp, const float* __restrict__ scl,
                           const float* __restrict__ shf, const float* __restrict__ W2,
                           const float* __restrict__ b2, float* __restrict__ out, int B) {
    int i = blockIdx.x * blockDim.x + threadIdx.x;
    if (i >= B * NTASK) return;
    int g = i / NTASK, j = i % NTASK;
    float acc = b2[j];
    for (int k = 0; k < 256; ++k) {
        float v = relu_(tp[(size_t)g * 256 + k] * scl[k] + shf[k]);
        acc += v * W2[k * NTASK + j];
    }
    out[i] = acc;
}

extern "C" void kernel_launch(void* const* d_in, const int* in_sizes, int n_in,
                              void* d_out, int out_size, void* d_ws, size_t ws_size,
                              hipStream_t stream) {
    const float* x       = (const float*)d_in[0];
    const int*   eidx    = (const int*)d_in[1];
    const int*   eattr   = (const int*)d_in[2];
    const int*   batch   = (const int*)d_in[3];
    const float* gumbels = (const float*)d_in[5];
    const float* node_W  = (const float*)d_in[6];
    const float* node_b  = (const float*)d_in[7];
    const float* enc_eps = (const float*)d_in[8];
    const float* enc_edge= (const float*)d_in[9];
    const float* enc_W1  = (const float*)d_in[10];
    const float* enc_b1  = (const float*)d_in[11];
    const float* enc_bn1g= (const float*)d_in[12];
    const float* enc_bn1b= (const float*)d_in[13];
    const float* enc_W2  = (const float*)d_in[14];
    const float* enc_b2  = (const float*)d_in[15];
    const float* enc_bng = (const float*)d_in[16];
    const float* enc_bnb = (const float*)d_in[17];
    const float* rat_eps = (const float*)d_in[18];
    const float* rat_edge= (const float*)d_in[19];
    const float* rat_W1  = (const float*)d_in[20];
    const float* rat_b1  = (const float*)d_in[21];
    const float* rat_bn1g= (const float*)d_in[22];
    const float* rat_bn1b= (const float*)d_in[23];
    const float* rat_W2  = (const float*)d_in[24];
    const float* rat_b2  = (const float*)d_in[25];
    const float* rat_bng = (const float*)d_in[26];
    const float* rat_bnb = (const float*)d_in[27];
    const float* gate_W1 = (const float*)d_in[28];
    const float* gate_b1 = (const float*)d_in[29];
    const float* gate_bng= (const float*)d_in[30];
    const float* gate_bnb= (const float*)d_in[31];
    const float* gate_W2 = (const float*)d_in[32];
    const float* gate_b2 = (const float*)d_in[33];
    const float* pred_W1 = (const float*)d_in[34];
    const float* pred_b1 = (const float*)d_in[35];
    const float* pred_bng= (const float*)d_in[36];
    const float* pred_bnb= (const float*)d_in[37];
    const float* pred_W2 = (const float*)d_in[38];
    const float* pred_b2 = (const float*)d_in[39];
    float* out = (float*)d_out;

    const int N = in_sizes[0] / 4;
    const int E = in_sizes[2];
    const int B = NGRAPH;

    const int gM64  = (N + 63) / 64;
    const int gM128 = (N + 127) / 128;

    // workspace carve
    char* w = (char*)d_ws;
    auto alloc = [&](size_t bytes) {
        char* p = w;
        w += (bytes + 255) & ~(size_t)255;
        return p;
    };
    float* h     = (float*)alloc((size_t)N * DIM * 4);
    float* buf   = (float*)alloc((size_t)N * DIM * 4);
    char*  t1base= alloc((size_t)N * DIM2 * 4);
    float* gate  = (float*)alloc((size_t)N * 4);
    float* scl   = (float*)alloc(256 * 4);
    float* shf   = (float*)alloc(256 * 4);
    float* psum  = (float*)alloc((size_t)gM64 * 256 * 4);
    float* psq   = (float*)alloc((size_t)gM64 * 256 * 4);
    float* hr    = (float*)alloc((size_t)B * DIM * 4);
    float* tpred = (float*)alloc((size_t)B * DIM2 * 4);
    float* lossg = (float*)alloc((size_t)B * 4);
    int* deg     = (int*)alloc((size_t)N * 4);
    int* incl    = (int*)alloc((size_t)N * 4);
    int* cursor  = (int*)alloc((size_t)N * 4);
    int* rowptr  = (int*)alloc((size_t)(N + 1) * 4);
    int* bsum    = (int*)alloc(128 * 4);
    int* boff    = (int*)alloc(128 * 4);
    int* srcs    = (int*)alloc((size_t)E * 4);
    int* eas     = (int*)alloc((size_t)E * 4);
    int* gptr    = (int*)alloc((size_t)(B + 1) * 4);
    unsigned short* W1t = (unsigned short*)alloc((size_t)5 * DIM2 * DIM * 2);
    unsigned short* W2t = (unsigned short*)alloc((size_t)5 * DIM * DIM2 * 2);

    // t1 fp32 region (rationale/gate phase) aliased by encoder bf16 buffers:
    float* t1          = (float*)t1base;
    unsigned short* zb  = (unsigned short*)t1base;
    unsigned short* t1b = (unsigned short*)(t1base + (size_t)N * DIM * 2);
    unsigned short* hb  = (unsigned short*)(t1base + (size_t)N * (DIM + DIM2) * 2);

    const int NB = (N + 1023) / 1024;

    // ---- CSR build (by dst) ----
    hipMemsetAsync(deg, 0, (size_t)N * 4, stream);
    k_count_deg<<<(E + 255) / 256, 256, 0, stream>>>(eidx + E, deg, E);
    k_scan_block<<<NB, 1024, 0, stream>>>(deg, incl, bsum, N);
    k_scan_bsum<<<1, 128, 0, stream>>>(bsum, boff, NB);
    k_scan_final<<<(N + 255) / 256, 256, 0, stream>>>(incl, deg, boff, rowptr, cursor, N);
    k_fill_csr<<<(E + 255) / 256, 256, 0, stream>>>(eidx, eidx + E, eattr, cursor, srcs, eas, E);
    k_graph_ptr<<<(B + 256) / 256, 256, 0, stream>>>(batch, gptr, N, B);

    // ---- encoder weight conversion (transposed bf16) ----
    {
        long long tot1 = 5LL * DIM * DIM2;
        k_wconv<<<(int)((tot1 + 255) / 256), 256, 0, stream>>>(enc_W1, W1t, 5, DIM, DIM2);
        k_wconv<<<(int)((tot1 + 255) / 256), 256, 0, stream>>>(enc_W2, W2t, 5, DIM2, DIM);
    }

    const int gE4 = (N * (DIM / 4) + 255) / 256;

    // ---- rationale stack (fp32, fused stats) + gate ----
    k_h0<<<gE4, 256, 0, stream>>>(x, node_W, node_b, h, nullptr, N);
    for (int l = 0; l < 2; ++l) {
        k_aggregate<<<(N + 7) / 8, 256, 0, stream>>>(h, rowptr, srcs, eas, rat_edge, rat_eps, l, buf, N);
        k_mmf<128, 256, false, true><<<dim3(gM64, 2), 256, 0, stream>>>(
            buf, rat_W1 + (size_t)l * 128 * 256, rat_b1 + (size_t)l * 256, nullptr, nullptr,
            t1, psum, psq, N);
        k_stats_fin<<<256, 256, 0, stream>>>(psum, psq, rat_bn1g + (size_t)l * 256,
                                             rat_bn1b + (size_t)l * 256, scl, shf, N, 256, gM64);
        k_mmf<256, 128, true, true><<<dim3(gM64, 1), 256, 0, stream>>>(
            t1, rat_W2 + (size_t)l * 256 * 128, rat_b2 + (size_t)l * 128, scl, shf,
            buf, psum, psq, N);
        k_stats_fin<<<128, 256, 0, stream>>>(psum, psq, rat_bng + (size_t)l * 128,
                                             rat_bnb + (size_t)l * 128, scl, shf, N, 128, gM64);
        k_residual<<<gE4, 256, 0, stream>>>(buf, scl, shf, h, nullptr, N, (l < 1) ? 1 : 0);
    }
    k_mmf<128, 256, false, true><<<dim3(gM64, 2), 256, 0, stream>>>(
        h, gate_W1, gate_b1, nullptr, nullptr, t1, psum, psq, N);
    k_stats_fin<<<256, 256, 0, stream>>>(psum, psq, gate_bng, gate_bnb, scl, shf, N, 256, gM64);
    k_gate<<<(N + 3) / 4, 256, 0, stream>>>(t1, scl, shf, gate_W2, gate_b2, gumbels, gate, N);

    // ---- encoder stack (bf16 MFMA, fused stats) ----
    k_h0<<<gE4, 256, 0, stream>>>(x, node_W, node_b, h, hb, N);
    for (int l = 0; l < 5; ++l) {
        k_agg_bf<<<(N + 7) / 8, 256, 0, stream>>>(hb, rowptr, srcs, eas, enc_edge, enc_eps, l, zb, N);
        k_mm_bf<128, 256, false, true, true><<<dim3(gM128, 4), 256, 0, stream>>>(
            zb, W1t + (size_t)l * DIM2 * DIM, enc_b1 + (size_t)l * 256, nullptr, nullptr,
            t1b, psum, psq, N);
        k_stats_fin<<<256, 256, 0, stream>>>(psum, psq, enc_bn1g + (size_t)l * 256,
                                             enc_bn1b + (size_t)l * 256, scl, shf, N, 256, gM128);
        k_mm_bf<256, 128, true, false, true><<<dim3(gM128, 2), 256, 0, stream>>>(
            t1b, W2t + (size_t)l * DIM * DIM2, enc_b2 + (size_t)l * 128, scl, shf,
            buf, psum, psq, N);
        k_stats_fin<<<128, 256, 0, stream>>>(psum, psq, enc_bng + (size_t)l * 128,
                                             enc_bnb + (size_t)l * 128, scl, shf, N, 128, gM128);
        k_residual<<<gE4, 256, 0, stream>>>(buf, scl, shf, h, (l < 4) ? hb : nullptr, N, (l < 4) ? 1 : 0);
    }

    // ---- per-graph reductions + loss ----
    k_segreduce<<<B, 256, 0, stream>>>(h, gate, gptr, hr, lossg, B);
    k_loss<<<1, 256, 0, stream>>>(lossg, out, B);

    // ---- pred head (fp32, fused stats) ----
    {
        const int gMB = (B + 63) / 64;
        k_mmf<128, 256, false, true><<<dim3(gMB, 2), 256, 0, stream>>>(
            hr, pred_W1, pred_b1, nullptr, nullptr, tpred, psum, psq, B);
        k_stats_fin<<<256, 256, 0, stream>>>(psum, psq, pred_bng, pred_bnb, scl, shf, B, 256, gMB);
        k_pred_out<<<(B * NTASK + 255) / 256, 256, 0, stream>>>(tpred, scl, shf, pred_W2,
                                                                pred_b2, out, B);
    }
}